// Round 15
// baseline (156.367 us; speedup 1.0000x reference)
//
#include <hip/hip_runtime.h>

#define NNODES 64000
#define NGRAPHS 128
#define D 64
#define NT 250        // teams (node-range partitions), team = d >> 8
#define ESEG 5120     // per-team elist capacity (mean 4096, sigma ~63)
#define ZG 1024       // zpool grid

typedef _Float16 half8 __attribute__((ext_vector_type(8)));
typedef float f32x4 __attribute__((ext_vector_type(4)));

__device__ __forceinline__ int lower_bound(const int* __restrict__ a, int n, int key) {
    int lo = 0, hi = n;
    while (lo < hi) {
        int mid = (lo + hi) >> 1;
        if (a[mid] < key) lo = mid + 1; else hi = mid;
    }
    return lo;
}

// ---- conversions (+ zero ecur/pool for later passes) -----------------------

__global__ void tohalf_kernel(const float4* __restrict__ x, half8* __restrict__ xh, int n8,
                              const float* __restrict__ Wl, const float* __restrict__ Wr,
                              _Float16* __restrict__ Wlh, _Float16* __restrict__ Wrh,
                              int* __restrict__ ecur, float* __restrict__ pool) {
    int i = blockIdx.x * blockDim.x + threadIdx.x;
    int st = gridDim.x * blockDim.x;
    for (; i < n8; i += st) {
        float4 a = x[2 * i], b = x[2 * i + 1];
        half8 o;
        o[0] = (_Float16)a.x; o[1] = (_Float16)a.y; o[2] = (_Float16)a.z; o[3] = (_Float16)a.w;
        o[4] = (_Float16)b.x; o[5] = (_Float16)b.y; o[6] = (_Float16)b.z; o[7] = (_Float16)b.w;
        xh[i] = o;
    }
    int j = blockIdx.x * blockDim.x + threadIdx.x;
    if (j < 3 * D * D) {
        Wlh[j] = (_Float16)Wl[j];
        Wrh[j] = (_Float16)Wr[j];
    }
    if (blockIdx.x == 0 && threadIdx.x < 256) {
        ecur[threadIdx.x] = 0;
        pool[threadIdx.x] = 0.f;
    }
}

// ---- partition: bin edges by dst>>8 into 250 contiguous lists --------------
// U=16: one 4096-edge chunk per block; one cursor claim per team per block.
__global__ __launch_bounds__(256) void partition_kernel(
        const int* __restrict__ src, const int* __restrict__ dst, int E,
        int* __restrict__ ecur, int2* __restrict__ elist) {
    __shared__ int bcnt[256], bbase[256];
    const int U = 16;
    int tid = threadIdx.x;
    int base = blockIdx.x * 256 * U;
    bcnt[tid] = 0;
    __syncthreads();
    int2 ed[U]; int team[U], slot[U];
#pragma unroll
    for (int u = 0; u < U; ++u) {
        int e = base + tid + u * 256;
        team[u] = -1;
        if (e < E) {
            int s = __builtin_nontemporal_load(src + e);
            int d = __builtin_nontemporal_load(dst + e);
            ed[u] = make_int2(s, d);
            team[u] = d >> 8;
            slot[u] = atomicAdd(&bcnt[team[u]], 1);
        }
    }
    __syncthreads();
    if (bcnt[tid] > 0) bbase[tid] = atomicAdd(&ecur[tid], bcnt[tid]);
    __syncthreads();
#pragma unroll
    for (int u = 0; u < U; ++u)
        if (team[u] >= 0)
            elist[(size_t)team[u] * ESEG + bbase[team[u]] + slot[u]] = ed[u];
}

// ---- per-team CSR fill: elist staged in LDS, all per-edge atomics in LDS ---
__global__ __launch_bounds__(1024) void fill_block(
        const int2* __restrict__ elist, const int* __restrict__ ecur,
        const int* __restrict__ batch,
        int* __restrict__ offs, int2* __restrict__ info, int* __restrict__ col) {
    __shared__ int2 els[ESEG];                 // 40 KB staging
    __shared__ int lhist[256], lofs[256];
    int team = blockIdx.x;
    int t = threadIdx.x;
    int n = ecur[team];
    const int2* el = elist + (size_t)team * ESEG;

    // team-base scan (redundant per block, 1KB read, trivial)
    if (t < 256) lofs[t] = (t < NT) ? ecur[t] : 0;
    __syncthreads();
    for (int off = 1; off < 256; off <<= 1) {
        int x = 0;
        if (t < 256 && t >= off) x = lofs[t - off];
        __syncthreads();
        if (t < 256) lofs[t] += x;
        __syncthreads();
    }
    int tb = (team > 0) ? lofs[team - 1] : 0;
    if (team == NT - 1 && t == 0) offs[NNODES] = lofs[NT - 1];
    __syncthreads();

    if (t < 256) lhist[t] = 0;
    __syncthreads();
    for (int e = t; e < n; e += 1024) {
        int2 ed = el[e];
        els[e] = ed;
        atomicAdd(&lhist[ed.y & 255], 1);
    }
    __syncthreads();
    if (t < 256) lofs[t] = lhist[t];
    __syncthreads();
    for (int off = 1; off < 256; off <<= 1) {
        int x = 0;
        if (t < 256 && t >= off) x = lofs[t - off];
        __syncthreads();
        if (t < 256) lofs[t] += x;
        __syncthreads();
    }
    if (t < 256) {
        int v = lhist[t];
        int ex = lofs[t] - v;          // exclusive
        int gi = team * 256 + t;
        offs[gi] = tb + ex;
        float inv = (v > 0) ? 1.f / (float)v : 0.f;
        info[gi] = make_int2(batch[gi], __float_as_int(inv));
        lofs[t] = ex;                  // becomes write cursor
    }
    __syncthreads();
    for (int e = t; e < n; e += 1024) {
        int2 ed = els[e];
        int p = tb + atomicAdd(&lofs[ed.y & 255], 1);
        col[p] = ed.x;
    }
}

// ---- fused layer: single-pass 16-node gather -> LDS tile -> MFMA ----------
// lane = (node-slot 0..15, 32B chunk 0..3); each lane owns 16 halfs of a row.
template <int PRJ>
__global__ __launch_bounds__(256) void layer_fused(
        const _Float16* __restrict__ h, _Float16* __restrict__ out,
        const int* __restrict__ offs, const int* __restrict__ col,
        const _Float16* __restrict__ Wlh, const _Float16* __restrict__ Wrh,
        const float* __restrict__ b,
        const float* __restrict__ Wlo, const float* __restrict__ Wro,
        float* __restrict__ z12, float* __restrict__ z34) {
    __shared__ _Float16 tile[4][16][D];          // 8 KB: per-wave 16x64 staging
    int lane = threadIdx.x & 63;
    int w    = threadIdx.x >> 6;
    int row0 = (blockIdx.x * 4 + w) * 16;

    // phase A: gather-mean, all 16 nodes in parallel
    {
        int ns  = lane >> 2;      // node slot 0..15
        int ch2 = lane & 3;       // 32B chunk 0..3
        int i = row0 + ns;
        int beg = offs[i], end = offs[i + 1];
        half8 s0 = {0, 0, 0, 0, 0, 0, 0, 0};
        half8 s1 = {0, 0, 0, 0, 0, 0, 0, 0};
        int e = beg;
        for (; e + 4 <= end; e += 4) {           // 8 x 16B loads in flight
            int c0 = col[e], c1 = col[e + 1], c2 = col[e + 2], c3 = col[e + 3];
            const _Float16* r0 = h + (size_t)c0 * D + ch2 * 16;
            const _Float16* r1 = h + (size_t)c1 * D + ch2 * 16;
            const _Float16* r2 = h + (size_t)c2 * D + ch2 * 16;
            const _Float16* r3 = h + (size_t)c3 * D + ch2 * 16;
            half8 a0 = *(const half8*)r0,       a1 = *(const half8*)r1;
            half8 a2 = *(const half8*)r2,       a3 = *(const half8*)r3;
            half8 b0 = *(const half8*)(r0 + 8), b1 = *(const half8*)(r1 + 8);
            half8 b2 = *(const half8*)(r2 + 8), b3 = *(const half8*)(r3 + 8);
            s0 += (a0 + a1) + (a2 + a3);         // v_pk_add_f16 tree
            s1 += (b0 + b1) + (b2 + b3);
        }
        for (; e < end; ++e) {
            const _Float16* rp = h + (size_t)col[e] * D + ch2 * 16;
            s0 += *(const half8*)rp;
            s1 += *(const half8*)(rp + 8);
        }
        float inv = (end > beg) ? 1.f / (float)(end - beg) : 0.f;
        half8 o0, o1;
#pragma unroll
        for (int j = 0; j < 8; ++j) {
            o0[j] = (_Float16)((float)s0[j] * inv);
            o1[j] = (_Float16)((float)s1[j] * inv);
        }
        *(half8*)(&tile[w][ns][ch2 * 16])     = o0;
        *(half8*)(&tile[w][ns][ch2 * 16 + 8]) = o1;
    }
    // wave-private tile; DS ops complete in issue order per wave -> no barrier.

    int r = lane & 15;        // A-row / B-col / C-col
    int g = lane >> 4;        // k-subgroup

    // B fragments: [Wl;Wr] rows, K=128 split in 4 chunks of 32
    half8 bf[4][4];
#pragma unroll
    for (int kt = 0; kt < 4; ++kt) {
        const _Float16* Wm = (kt < 2) ? Wlh : Wrh;
        int kk = (kt & 1) * 32 + g * 8;
#pragma unroll
        for (int nt = 0; nt < 4; ++nt)
            bf[kt][nt] = *(const half8*)(Wm + (size_t)(nt * 16 + r) * D + kk);
    }

    f32x4 acc[4];
#pragma unroll
    for (int nt = 0; nt < 4; ++nt) {
        float bv = b[nt * 16 + r];
        acc[nt] = (f32x4){bv, bv, bv, bv};
    }

#pragma unroll
    for (int kt = 0; kt < 4; ++kt) {
        int kk = (kt & 1) * 32 + g * 8;
        half8 af;
        if (kt < 2) af = *(const half8*)(&tile[w][r][kk]);                 // aggr
        else        af = *(const half8*)(h + (size_t)(row0 + r) * D + kk); // self
#pragma unroll
        for (int nt = 0; nt < 4; ++nt)
            acc[nt] = __builtin_amdgcn_mfma_f32_16x16x32_f16(af, bf[kt][nt], acc[nt], 0, 0, 0);
    }

    // epilogue. C/D: col = lane&15, row = (lane>>4)*4 + q  [m89-verified]
    if (!PRJ) {
#pragma unroll
        for (int nt = 0; nt < 4; ++nt)
#pragma unroll
            for (int q = 0; q < 4; ++q) {
                int row = row0 + g * 4 + q;
                out[(size_t)row * D + nt * 16 + r] = (_Float16)fmaxf(acc[nt][q], 0.f);
            }
    } else {
        // stage relu(out) tile back to LDS (wave-private, in-order DS)
#pragma unroll
        for (int nt = 0; nt < 4; ++nt)
#pragma unroll
            for (int q = 0; q < 4; ++q)
                tile[w][g * 4 + q][nt * 16 + r] = (_Float16)fmaxf(acc[nt][q], 0.f);

        // B-frag of P rows {Wlo0,Wlo1,Wro0,Wro1} in cols 0..3
        half8 pf[2];
#pragma unroll
        for (int kt = 0; kt < 2; ++kt) {
            half8 t = {0, 0, 0, 0, 0, 0, 0, 0};
            if (r < 4) {
                const float* Pr = (r < 2) ? (Wlo + r * D) : (Wro + (r - 2) * D);
                int kk = kt * 32 + g * 8;
#pragma unroll
                for (int j = 0; j < 8; ++j) t[j] = (_Float16)Pr[kk + j];
            }
            pf[kt] = t;
        }
        f32x4 az = (f32x4){0.f, 0.f, 0.f, 0.f};
#pragma unroll
        for (int kt = 0; kt < 2; ++kt) {
            half8 af = *(const half8*)(&tile[w][r][kt * 32 + g * 8]);
            az = __builtin_amdgcn_mfma_f32_16x16x32_f16(af, pf[kt], az, 0, 0, 0);
        }
#pragma unroll
        for (int q = 0; q < 4; ++q) {
            int row = row0 + g * 4 + q;
            if (r < 2)      z12[row * 2 + r]       = az[q];
            else if (r < 4) z34[row * 2 + (r - 2)] = az[q];
        }
    }
}

// ---- edge-parallel pool: LDS partials + one global atomic per slot/block ---
__global__ __launch_bounds__(256) void zpool_edge(
        const float2* __restrict__ z12, const float2* __restrict__ z34,
        const int* __restrict__ src, const int* __restrict__ dst,
        const int2* __restrict__ info, int E, float* __restrict__ pool) {
    __shared__ float lp[NGRAPHS * 2];
    int t = threadIdx.x;
    lp[t] = 0.f;
    __syncthreads();
    int tid = blockIdx.x * blockDim.x + t;
    int stride = gridDim.x * blockDim.x;
    for (int e = tid; e < E; e += stride) {
        int s = __builtin_nontemporal_load(src + e);
        int d = __builtin_nontemporal_load(dst + e);
        float2 z = z12[s];
        int2 nf = info[d];
        float w = __int_as_float(nf.y);
        atomicAdd(&lp[0 * NGRAPHS + nf.x], z.x * w);
        atomicAdd(&lp[1 * NGRAPHS + nf.x], z.y * w);
    }
    for (int i = tid; i < NNODES; i += stride) {
        float2 zi = z34[i];
        int g = info[i].x;
        atomicAdd(&lp[0 * NGRAPHS + g], zi.x);
        atomicAdd(&lp[1 * NGRAPHS + g], zi.y);
    }
    __syncthreads();
    float v = lp[t];
    if (v != 0.f) atomicAdd(&pool[t], v);
}

// ---- final: 1KB read, scale+bias ------------------------------------------
__global__ void out_kernel(const float* __restrict__ pool, const int* __restrict__ batch,
                           const float* __restrict__ bo, float* __restrict__ out) {
    int t = threadIdx.x;              // slot (j*128+g)
    float v = pool[t];
    int j = t >> 7, g = t & 127;
    int c = lower_bound(batch, NNODES, g + 1) - lower_bound(batch, NNODES, g);
    out[g * 2 + j] = (c > 0) ? v / (float)c + bo[j] : 0.f;
}

// ---- launch ---------------------------------------------------------------

extern "C" void kernel_launch(void* const* d_in, const int* in_sizes, int n_in,
                              void* d_out, int out_size, void* d_ws, size_t ws_size,
                              hipStream_t stream) {
    const float* x    = (const float*)d_in[0];
    const int*   eidx = (const int*)d_in[1];
    const int*   batch= (const int*)d_in[2];
    const float* Wl   = (const float*)d_in[3];
    const float* Wr   = (const float*)d_in[4];
    const float* b    = (const float*)d_in[5];
    const float* Wlo  = (const float*)d_in[6];
    const float* Wro  = (const float*)d_in[7];
    const float* bo   = (const float*)d_in[8];

    int E = in_sizes[1] / 2;
    const int* src = eidx;
    const int* dst = eidx + E;

    char* ws = (char*)d_ws;
    size_t hb = (size_t)NNODES * D * 2;       // fp16 h buffer = 8,192,000 B
    _Float16* xh   = (_Float16*)ws;
    _Float16* bufA = (_Float16*)(ws + hb);
    char* p = ws + 2 * hb;
    _Float16* Wlh  = (_Float16*)p;  p += 3 * D * D * 2;
    _Float16* Wrh  = (_Float16*)p;  p += 3 * D * D * 2;
    int*    col  = (int*)p;     p += (size_t)E * 4;
    int*    offs = (int*)p;     p += ((size_t)(NNODES + 1) * 4 + 127) / 128 * 128;
    int2*   info = (int2*)p;    p += (size_t)NNODES * 8;
    float*  z12  = (float*)p;   p += (size_t)NNODES * 8;
    float*  z34  = (float*)p;   p += (size_t)NNODES * 8;
    int*    ecur = (int*)p;     p += 1024;
    float*  pool = (float*)p;   p += 1024;
    int2*   elist= (int2*)p;    // 250 * 5120 * 8 = 10.24 MB

    tohalf_kernel<<<2000, 256, 0, stream>>>((const float4*)x, (half8*)xh, NNODES * D / 8,
                                            Wl, Wr, Wlh, Wrh, ecur, pool);

    int PB = (E + 4095) / 4096;      // 250 for E=1,024,000
    partition_kernel<<<PB, 256, 0, stream>>>(src, dst, E, ecur, elist);
    fill_block<<<NT, 1024, 0, stream>>>(elist, ecur, batch, offs, info, col);

    // L1: xh -> bufA ; L2: bufA -> xh ; L3: xh -> z12/z34 (no h3 materialized)
    layer_fused<0><<<1000, 256, 0, stream>>>(xh,   bufA, offs, col,
                                             Wlh,             Wrh,             b,
                                             nullptr, nullptr, nullptr, nullptr);
    layer_fused<0><<<1000, 256, 0, stream>>>(bufA, xh,   offs, col,
                                             Wlh + D * D,     Wrh + D * D,     b + D,
                                             nullptr, nullptr, nullptr, nullptr);
    layer_fused<1><<<1000, 256, 0, stream>>>(xh,   bufA, offs, col,
                                             Wlh + 2 * D * D, Wrh + 2 * D * D, b + 2 * D,
                                             Wlo, Wro, z12, z34);

    zpool_edge<<<ZG, 256, 0, stream>>>((const float2*)z12, (const float2*)z34,
                                       src, dst, info, E, pool);
    out_kernel<<<1, 256, 0, stream>>>(pool, batch, bo, (float*)d_out);
}

// Round 16
// 143.820 us; speedup vs baseline: 1.0872x; 1.0872x over previous
//
#include <hip/hip_runtime.h>

#define NNODES 64000
#define NGRAPHS 128
#define D 64
#define NT 250        // teams (node-range partitions), team = d >> 8
#define ESEG 5120     // per-team elist capacity (mean 4096, sigma ~63)
#define ZG 512        // zpool grid (atomic-tail chain length; R9-proven point)

typedef _Float16 half8 __attribute__((ext_vector_type(8)));
typedef float f32x4 __attribute__((ext_vector_type(4)));

__device__ __forceinline__ int lower_bound(const int* __restrict__ a, int n, int key) {
    int lo = 0, hi = n;
    while (lo < hi) {
        int mid = (lo + hi) >> 1;
        if (a[mid] < key) lo = mid + 1; else hi = mid;
    }
    return lo;
}

// ---- conversions (+ zero ecur/pool for later passes) -----------------------

__global__ void tohalf_kernel(const float4* __restrict__ x, half8* __restrict__ xh, int n8,
                              const float* __restrict__ Wl, const float* __restrict__ Wr,
                              _Float16* __restrict__ Wlh, _Float16* __restrict__ Wrh,
                              int* __restrict__ ecur, float* __restrict__ pool) {
    int i = blockIdx.x * blockDim.x + threadIdx.x;
    int st = gridDim.x * blockDim.x;
    for (; i < n8; i += st) {
        float4 a = x[2 * i], b = x[2 * i + 1];
        half8 o;
        o[0] = (_Float16)a.x; o[1] = (_Float16)a.y; o[2] = (_Float16)a.z; o[3] = (_Float16)a.w;
        o[4] = (_Float16)b.x; o[5] = (_Float16)b.y; o[6] = (_Float16)b.z; o[7] = (_Float16)b.w;
        xh[i] = o;
    }
    int j = blockIdx.x * blockDim.x + threadIdx.x;
    if (j < 3 * D * D) {
        Wlh[j] = (_Float16)Wl[j];
        Wrh[j] = (_Float16)Wr[j];
    }
    if (blockIdx.x == 0 && threadIdx.x < 256) {
        ecur[threadIdx.x] = 0;
        pool[threadIdx.x] = 0.f;
    }
}

// ---- partition: bin edges by dst>>8 into 250 contiguous lists --------------
// U=16: one 4096-edge chunk per block; one cursor claim per team per block.
__global__ __launch_bounds__(256) void partition_kernel(
        const int* __restrict__ src, const int* __restrict__ dst, int E,
        int* __restrict__ ecur, int2* __restrict__ elist) {
    __shared__ int bcnt[256], bbase[256];
    const int U = 16;
    int tid = threadIdx.x;
    int base = blockIdx.x * 256 * U;
    bcnt[tid] = 0;
    __syncthreads();
    int2 ed[U]; int team[U], slot[U];
#pragma unroll
    for (int u = 0; u < U; ++u) {
        int e = base + tid + u * 256;
        team[u] = -1;
        if (e < E) {
            int s = __builtin_nontemporal_load(src + e);
            int d = __builtin_nontemporal_load(dst + e);
            ed[u] = make_int2(s, d);
            team[u] = d >> 8;
            slot[u] = atomicAdd(&bcnt[team[u]], 1);
        }
    }
    __syncthreads();
    if (bcnt[tid] > 0) bbase[tid] = atomicAdd(&ecur[tid], bcnt[tid]);
    __syncthreads();
#pragma unroll
    for (int u = 0; u < U; ++u)
        if (team[u] >= 0)
            elist[(size_t)team[u] * ESEG + bbase[team[u]] + slot[u]] = ed[u];
}

// ---- per-team CSR fill: elist staged in LDS, all per-edge atomics in LDS ---
__global__ __launch_bounds__(1024) void fill_block(
        const int2* __restrict__ elist, const int* __restrict__ ecur,
        const int* __restrict__ batch,
        int* __restrict__ offs, int2* __restrict__ info, int* __restrict__ col) {
    __shared__ int2 els[ESEG];                 // 40 KB staging
    __shared__ int lhist[256], lofs[256];
    int team = blockIdx.x;
    int t = threadIdx.x;
    int n = ecur[team];
    const int2* el = elist + (size_t)team * ESEG;

    // team-base scan (redundant per block, 1KB read, trivial)
    if (t < 256) lofs[t] = (t < NT) ? ecur[t] : 0;
    __syncthreads();
    for (int off = 1; off < 256; off <<= 1) {
        int x = 0;
        if (t < 256 && t >= off) x = lofs[t - off];
        __syncthreads();
        if (t < 256) lofs[t] += x;
        __syncthreads();
    }
    int tb = (team > 0) ? lofs[team - 1] : 0;
    if (team == NT - 1 && t == 0) offs[NNODES] = lofs[NT - 1];
    __syncthreads();

    if (t < 256) lhist[t] = 0;
    __syncthreads();
    for (int e = t; e < n; e += 1024) {
        int2 ed = el[e];
        els[e] = ed;
        atomicAdd(&lhist[ed.y & 255], 1);
    }
    __syncthreads();
    if (t < 256) lofs[t] = lhist[t];
    __syncthreads();
    for (int off = 1; off < 256; off <<= 1) {
        int x = 0;
        if (t < 256 && t >= off) x = lofs[t - off];
        __syncthreads();
        if (t < 256) lofs[t] += x;
        __syncthreads();
    }
    if (t < 256) {
        int v = lhist[t];
        int ex = lofs[t] - v;          // exclusive
        int gi = team * 256 + t;
        offs[gi] = tb + ex;
        float inv = (v > 0) ? 1.f / (float)v : 0.f;
        info[gi] = make_int2(batch[gi], __float_as_int(inv));
        lofs[t] = ex;                  // becomes write cursor
    }
    __syncthreads();
    for (int e = t; e < n; e += 1024) {
        int2 ed = els[e];
        int p = tb + atomicAdd(&lofs[ed.y & 255], 1);
        col[p] = ed.x;
    }
}

// ---- fused layer: single-pass 16-node gather -> LDS tile -> MFMA ----------
// lane = (node-slot 0..15, 32B chunk 0..3); each lane owns 16 halfs of a row.
template <int PRJ>
__global__ __launch_bounds__(256) void layer_fused(
        const _Float16* __restrict__ h, _Float16* __restrict__ out,
        const int* __restrict__ offs, const int* __restrict__ col,
        const _Float16* __restrict__ Wlh, const _Float16* __restrict__ Wrh,
        const float* __restrict__ b,
        const float* __restrict__ Wlo, const float* __restrict__ Wro,
        float* __restrict__ z12, float* __restrict__ z34) {
    __shared__ _Float16 tile[4][16][D];          // 8 KB: per-wave 16x64 staging
    int lane = threadIdx.x & 63;
    int w    = threadIdx.x >> 6;
    int row0 = (blockIdx.x * 4 + w) * 16;

    // phase A: gather-mean, all 16 nodes in parallel
    {
        int ns  = lane >> 2;      // node slot 0..15
        int ch2 = lane & 3;       // 32B chunk 0..3
        int i = row0 + ns;
        int beg = offs[i], end = offs[i + 1];
        half8 s0 = {0, 0, 0, 0, 0, 0, 0, 0};
        half8 s1 = {0, 0, 0, 0, 0, 0, 0, 0};
        int e = beg;
        for (; e + 4 <= end; e += 4) {           // 8 x 16B loads in flight
            int c0 = col[e], c1 = col[e + 1], c2 = col[e + 2], c3 = col[e + 3];
            const _Float16* r0 = h + (size_t)c0 * D + ch2 * 16;
            const _Float16* r1 = h + (size_t)c1 * D + ch2 * 16;
            const _Float16* r2 = h + (size_t)c2 * D + ch2 * 16;
            const _Float16* r3 = h + (size_t)c3 * D + ch2 * 16;
            half8 a0 = *(const half8*)r0,       a1 = *(const half8*)r1;
            half8 a2 = *(const half8*)r2,       a3 = *(const half8*)r3;
            half8 b0 = *(const half8*)(r0 + 8), b1 = *(const half8*)(r1 + 8);
            half8 b2 = *(const half8*)(r2 + 8), b3 = *(const half8*)(r3 + 8);
            s0 += (a0 + a1) + (a2 + a3);         // v_pk_add_f16 tree
            s1 += (b0 + b1) + (b2 + b3);
        }
        for (; e < end; ++e) {
            const _Float16* rp = h + (size_t)col[e] * D + ch2 * 16;
            s0 += *(const half8*)rp;
            s1 += *(const half8*)(rp + 8);
        }
        float inv = (end > beg) ? 1.f / (float)(end - beg) : 0.f;
        half8 o0, o1;
#pragma unroll
        for (int j = 0; j < 8; ++j) {
            o0[j] = (_Float16)((float)s0[j] * inv);
            o1[j] = (_Float16)((float)s1[j] * inv);
        }
        *(half8*)(&tile[w][ns][ch2 * 16])     = o0;
        *(half8*)(&tile[w][ns][ch2 * 16 + 8]) = o1;
    }
    // wave-private tile; DS ops complete in issue order per wave -> no barrier.

    int r = lane & 15;        // A-row / B-col / C-col
    int g = lane >> 4;        // k-subgroup

    // B fragments: [Wl;Wr] rows, K=128 split in 4 chunks of 32
    half8 bf[4][4];
#pragma unroll
    for (int kt = 0; kt < 4; ++kt) {
        const _Float16* Wm = (kt < 2) ? Wlh : Wrh;
        int kk = (kt & 1) * 32 + g * 8;
#pragma unroll
        for (int nt = 0; nt < 4; ++nt)
            bf[kt][nt] = *(const half8*)(Wm + (size_t)(nt * 16 + r) * D + kk);
    }

    f32x4 acc[4];
#pragma unroll
    for (int nt = 0; nt < 4; ++nt) {
        float bv = b[nt * 16 + r];
        acc[nt] = (f32x4){bv, bv, bv, bv};
    }

#pragma unroll
    for (int kt = 0; kt < 4; ++kt) {
        int kk = (kt & 1) * 32 + g * 8;
        half8 af;
        if (kt < 2) af = *(const half8*)(&tile[w][r][kk]);                 // aggr
        else        af = *(const half8*)(h + (size_t)(row0 + r) * D + kk); // self
#pragma unroll
        for (int nt = 0; nt < 4; ++nt)
            acc[nt] = __builtin_amdgcn_mfma_f32_16x16x32_f16(af, bf[kt][nt], acc[nt], 0, 0, 0);
    }

    // epilogue. C/D: col = lane&15, row = (lane>>4)*4 + q  [m89-verified]
    if (!PRJ) {
#pragma unroll
        for (int nt = 0; nt < 4; ++nt)
#pragma unroll
            for (int q = 0; q < 4; ++q) {
                int row = row0 + g * 4 + q;
                out[(size_t)row * D + nt * 16 + r] = (_Float16)fmaxf(acc[nt][q], 0.f);
            }
    } else {
        // stage relu(out) tile back to LDS (wave-private, in-order DS)
#pragma unroll
        for (int nt = 0; nt < 4; ++nt)
#pragma unroll
            for (int q = 0; q < 4; ++q)
                tile[w][g * 4 + q][nt * 16 + r] = (_Float16)fmaxf(acc[nt][q], 0.f);

        // B-frag of P rows {Wlo0,Wlo1,Wro0,Wro1} in cols 0..3
        half8 pf[2];
#pragma unroll
        for (int kt = 0; kt < 2; ++kt) {
            half8 t = {0, 0, 0, 0, 0, 0, 0, 0};
            if (r < 4) {
                const float* Pr = (r < 2) ? (Wlo + r * D) : (Wro + (r - 2) * D);
                int kk = kt * 32 + g * 8;
#pragma unroll
                for (int j = 0; j < 8; ++j) t[j] = (_Float16)Pr[kk + j];
            }
            pf[kt] = t;
        }
        f32x4 az = (f32x4){0.f, 0.f, 0.f, 0.f};
#pragma unroll
        for (int kt = 0; kt < 2; ++kt) {
            half8 af = *(const half8*)(&tile[w][r][kt * 32 + g * 8]);
            az = __builtin_amdgcn_mfma_f32_16x16x32_f16(af, pf[kt], az, 0, 0, 0);
        }
#pragma unroll
        for (int q = 0; q < 4; ++q) {
            int row = row0 + g * 4 + q;
            if (r < 2)      z12[row * 2 + r]       = az[q];
            else if (r < 4) z34[row * 2 + (r - 2)] = az[q];
        }
    }
}

// ---- edge-parallel pool: LDS partials + one global atomic per slot/block ---
__global__ __launch_bounds__(256) void zpool_edge(
        const float2* __restrict__ z12, const float2* __restrict__ z34,
        const int* __restrict__ src, const int* __restrict__ dst,
        const int2* __restrict__ info, int E, float* __restrict__ pool) {
    __shared__ float lp[NGRAPHS * 2];
    int t = threadIdx.x;
    lp[t] = 0.f;
    __syncthreads();
    int tid = blockIdx.x * blockDim.x + t;
    int stride = gridDim.x * blockDim.x;
    for (int e = tid; e < E; e += stride) {
        int s = __builtin_nontemporal_load(src + e);
        int d = __builtin_nontemporal_load(dst + e);
        float2 z = z12[s];
        int2 nf = info[d];
        float w = __int_as_float(nf.y);
        atomicAdd(&lp[0 * NGRAPHS + nf.x], z.x * w);
        atomicAdd(&lp[1 * NGRAPHS + nf.x], z.y * w);
    }
    for (int i = tid; i < NNODES; i += stride) {
        float2 zi = z34[i];
        int g = info[i].x;
        atomicAdd(&lp[0 * NGRAPHS + g], zi.x);
        atomicAdd(&lp[1 * NGRAPHS + g], zi.y);
    }
    __syncthreads();
    float v = lp[t];
    if (v != 0.f) atomicAdd(&pool[t], v);
}

// ---- final: 1KB read, scale+bias ------------------------------------------
__global__ void out_kernel(const float* __restrict__ pool, const int* __restrict__ batch,
                           const float* __restrict__ bo, float* __restrict__ out) {
    int t = threadIdx.x;              // slot (j*128+g)
    float v = pool[t];
    int j = t >> 7, g = t & 127;
    int c = lower_bound(batch, NNODES, g + 1) - lower_bound(batch, NNODES, g);
    out[g * 2 + j] = (c > 0) ? v / (float)c + bo[j] : 0.f;
}

// ---- launch ---------------------------------------------------------------

extern "C" void kernel_launch(void* const* d_in, const int* in_sizes, int n_in,
                              void* d_out, int out_size, void* d_ws, size_t ws_size,
                              hipStream_t stream) {
    const float* x    = (const float*)d_in[0];
    const int*   eidx = (const int*)d_in[1];
    const int*   batch= (const int*)d_in[2];
    const float* Wl   = (const float*)d_in[3];
    const float* Wr   = (const float*)d_in[4];
    const float* b    = (const float*)d_in[5];
    const float* Wlo  = (const float*)d_in[6];
    const float* Wro  = (const float*)d_in[7];
    const float* bo   = (const float*)d_in[8];

    int E = in_sizes[1] / 2;
    const int* src = eidx;
    const int* dst = eidx + E;

    char* ws = (char*)d_ws;
    size_t hb = (size_t)NNODES * D * 2;       // fp16 h buffer = 8,192,000 B
    _Float16* xh   = (_Float16*)ws;
    _Float16* bufA = (_Float16*)(ws + hb);
    char* p = ws + 2 * hb;
    _Float16* Wlh  = (_Float16*)p;  p += 3 * D * D * 2;
    _Float16* Wrh  = (_Float16*)p;  p += 3 * D * D * 2;
    int*    col  = (int*)p;     p += (size_t)E * 4;
    int*    offs = (int*)p;     p += ((size_t)(NNODES + 1) * 4 + 127) / 128 * 128;
    int2*   info = (int2*)p;    p += (size_t)NNODES * 8;
    float*  z12  = (float*)p;   p += (size_t)NNODES * 8;
    float*  z34  = (float*)p;   p += (size_t)NNODES * 8;
    int*    ecur = (int*)p;     p += 1024;
    float*  pool = (float*)p;   p += 1024;
    int2*   elist= (int2*)p;    // 250 * 5120 * 8 = 10.24 MB

    tohalf_kernel<<<2000, 256, 0, stream>>>((const float4*)x, (half8*)xh, NNODES * D / 8,
                                            Wl, Wr, Wlh, Wrh, ecur, pool);

    int PB = (E + 4095) / 4096;      // 250 for E=1,024,000
    partition_kernel<<<PB, 256, 0, stream>>>(src, dst, E, ecur, elist);
    fill_block<<<NT, 1024, 0, stream>>>(elist, ecur, batch, offs, info, col);

    // L1: xh -> bufA ; L2: bufA -> xh ; L3: xh -> z12/z34 (no h3 materialized)
    layer_fused<0><<<1000, 256, 0, stream>>>(xh,   bufA, offs, col,
                                             Wlh,             Wrh,             b,
                                             nullptr, nullptr, nullptr, nullptr);
    layer_fused<0><<<1000, 256, 0, stream>>>(bufA, xh,   offs, col,
                                             Wlh + D * D,     Wrh + D * D,     b + D,
                                             nullptr, nullptr, nullptr, nullptr);
    layer_fused<1><<<1000, 256, 0, stream>>>(xh,   bufA, offs, col,
                                             Wlh + 2 * D * D, Wrh + 2 * D * D, b + 2 * D,
                                             Wlo, Wro, z12, z34);

    zpool_edge<<<ZG, 256, 0, stream>>>((const float2*)z12, (const float2*)z34,
                                       src, dst, info, E, pool);
    out_kernel<<<1, 256, 0, stream>>>(pool, batch, bo, (float*)d_out);
}

// Round 17
// 136.731 us; speedup vs baseline: 1.1436x; 1.0519x over previous
//
#include <hip/hip_runtime.h>

#define NNODES 64000
#define NGRAPHS 128
#define D 64
#define NT 250        // teams (node-range partitions), team = d >> 8
#define ESEG 5120     // per-team elist capacity (mean 4096, sigma ~63)
#define ZG 1024       // zpool grid
#define NPOOL 8       // pool split ways (atomic chain = ZG/NPOOL)
#define CGRID 2000    // convert-role blocks in fat kernel

typedef _Float16 half8 __attribute__((ext_vector_type(8)));
typedef float f32x4 __attribute__((ext_vector_type(4)));

__device__ __forceinline__ int lower_bound(const int* __restrict__ a, int n, int key) {
    int lo = 0, hi = n;
    while (lo < hi) {
        int mid = (lo + hi) >> 1;
        if (a[mid] < key) lo = mid + 1; else hi = mid;
    }
    return lo;
}

// ---- fat kernel: edge partition (blocks 0..PB-1) ∥ f32->f16 convert (rest) -
// Roles touch disjoint data; both BW-bound; ecur pre-zeroed via memset.
__global__ __launch_bounds__(256) void convert_partition(
        const float4* __restrict__ x, half8* __restrict__ xh, int n8,
        const float* __restrict__ Wl, const float* __restrict__ Wr,
        _Float16* __restrict__ Wlh, _Float16* __restrict__ Wrh,
        const int* __restrict__ src, const int* __restrict__ dst, int E,
        int* __restrict__ ecur, int2* __restrict__ elist,
        float* __restrict__ pool, int PB) {
    __shared__ int bcnt[256], bbase[256];
    int tid = threadIdx.x;
    if ((int)blockIdx.x < PB) {
        // ---- partition role: U=16, one 4096-edge chunk per block
        const int U = 16;
        int base = blockIdx.x * 256 * U;
        bcnt[tid] = 0;
        __syncthreads();
        int2 ed[U]; int team[U], slot[U];
#pragma unroll
        for (int u = 0; u < U; ++u) {
            int e = base + tid + u * 256;
            team[u] = -1;
            if (e < E) {
                int s = __builtin_nontemporal_load(src + e);
                int d = __builtin_nontemporal_load(dst + e);
                ed[u] = make_int2(s, d);
                team[u] = d >> 8;
                slot[u] = atomicAdd(&bcnt[team[u]], 1);
            }
        }
        __syncthreads();
        if (bcnt[tid] > 0) bbase[tid] = atomicAdd(&ecur[tid], bcnt[tid]);
        __syncthreads();
#pragma unroll
        for (int u = 0; u < U; ++u)
            if (team[u] >= 0)
                elist[(size_t)team[u] * ESEG + bbase[team[u]] + slot[u]] = ed[u];
    } else {
        // ---- convert role
        int bid = blockIdx.x - PB;              // 0..CGRID-1
        int i = bid * 256 + tid;
        int st = CGRID * 256;
        for (; i < n8; i += st) {
            float4 a = x[2 * i], b = x[2 * i + 1];
            half8 o;
            o[0] = (_Float16)a.x; o[1] = (_Float16)a.y; o[2] = (_Float16)a.z; o[3] = (_Float16)a.w;
            o[4] = (_Float16)b.x; o[5] = (_Float16)b.y; o[6] = (_Float16)b.z; o[7] = (_Float16)b.w;
            xh[i] = o;
        }
        int j = bid * 256 + tid;
        if (j < 3 * D * D) {
            Wlh[j] = (_Float16)Wl[j];
            Wrh[j] = (_Float16)Wr[j];
        }
        if (bid == 0) {
#pragma unroll
            for (int k = 0; k < NPOOL; ++k) pool[k * 256 + tid] = 0.f;
        }
    }
}

// ---- per-team CSR fill: elist staged in LDS, all per-edge atomics in LDS ---
__global__ __launch_bounds__(1024) void fill_block(
        const int2* __restrict__ elist, const int* __restrict__ ecur,
        const int* __restrict__ batch,
        int* __restrict__ offs, int2* __restrict__ info, int* __restrict__ col) {
    __shared__ int2 els[ESEG];                 // 40 KB staging
    __shared__ int lhist[256], lofs[256];
    int team = blockIdx.x;
    int t = threadIdx.x;
    int n = ecur[team];
    const int2* el = elist + (size_t)team * ESEG;

    // team-base scan (redundant per block, 1KB read, trivial)
    if (t < 256) lofs[t] = (t < NT) ? ecur[t] : 0;
    __syncthreads();
    for (int off = 1; off < 256; off <<= 1) {
        int x = 0;
        if (t < 256 && t >= off) x = lofs[t - off];
        __syncthreads();
        if (t < 256) lofs[t] += x;
        __syncthreads();
    }
    int tb = (team > 0) ? lofs[team - 1] : 0;
    if (team == NT - 1 && t == 0) offs[NNODES] = lofs[NT - 1];
    __syncthreads();

    if (t < 256) lhist[t] = 0;
    __syncthreads();
    for (int e = t; e < n; e += 1024) {
        int2 ed = el[e];
        els[e] = ed;
        atomicAdd(&lhist[ed.y & 255], 1);
    }
    __syncthreads();
    if (t < 256) lofs[t] = lhist[t];
    __syncthreads();
    for (int off = 1; off < 256; off <<= 1) {
        int x = 0;
        if (t < 256 && t >= off) x = lofs[t - off];
        __syncthreads();
        if (t < 256) lofs[t] += x;
        __syncthreads();
    }
    if (t < 256) {
        int v = lhist[t];
        int ex = lofs[t] - v;          // exclusive
        int gi = team * 256 + t;
        offs[gi] = tb + ex;
        float inv = (v > 0) ? 1.f / (float)v : 0.f;
        info[gi] = make_int2(batch[gi], __float_as_int(inv));
        lofs[t] = ex;                  // becomes write cursor
    }
    __syncthreads();
    for (int e = t; e < n; e += 1024) {
        int2 ed = els[e];
        int p = tb + atomicAdd(&lofs[ed.y & 255], 1);
        col[p] = ed.x;
    }
}

// ---- fused layer: single-pass 16-node gather -> LDS tile -> MFMA ----------
// lane = (node-slot 0..15, 32B chunk 0..3); each lane owns 16 halfs of a row.
template <int PRJ>
__global__ __launch_bounds__(256) void layer_fused(
        const _Float16* __restrict__ h, _Float16* __restrict__ out,
        const int* __restrict__ offs, const int* __restrict__ col,
        const _Float16* __restrict__ Wlh, const _Float16* __restrict__ Wrh,
        const float* __restrict__ b,
        const float* __restrict__ Wlo, const float* __restrict__ Wro,
        float* __restrict__ z12, float* __restrict__ z34) {
    __shared__ _Float16 tile[4][16][D];          // 8 KB: per-wave 16x64 staging
    int lane = threadIdx.x & 63;
    int w    = threadIdx.x >> 6;
    int row0 = (blockIdx.x * 4 + w) * 16;

    // phase A: gather-mean, all 16 nodes in parallel
    {
        int ns  = lane >> 2;      // node slot 0..15
        int ch2 = lane & 3;       // 32B chunk 0..3
        int i = row0 + ns;
        int beg = offs[i], end = offs[i + 1];
        half8 s0 = {0, 0, 0, 0, 0, 0, 0, 0};
        half8 s1 = {0, 0, 0, 0, 0, 0, 0, 0};
        int e = beg;
        for (; e + 4 <= end; e += 4) {           // 8 x 16B loads in flight
            int c0 = col[e], c1 = col[e + 1], c2 = col[e + 2], c3 = col[e + 3];
            const _Float16* r0 = h + (size_t)c0 * D + ch2 * 16;
            const _Float16* r1 = h + (size_t)c1 * D + ch2 * 16;
            const _Float16* r2 = h + (size_t)c2 * D + ch2 * 16;
            const _Float16* r3 = h + (size_t)c3 * D + ch2 * 16;
            half8 a0 = *(const half8*)r0,       a1 = *(const half8*)r1;
            half8 a2 = *(const half8*)r2,       a3 = *(const half8*)r3;
            half8 b0 = *(const half8*)(r0 + 8), b1 = *(const half8*)(r1 + 8);
            half8 b2 = *(const half8*)(r2 + 8), b3 = *(const half8*)(r3 + 8);
            s0 += (a0 + a1) + (a2 + a3);         // v_pk_add_f16 tree
            s1 += (b0 + b1) + (b2 + b3);
        }
        for (; e < end; ++e) {
            const _Float16* rp = h + (size_t)col[e] * D + ch2 * 16;
            s0 += *(const half8*)rp;
            s1 += *(const half8*)(rp + 8);
        }
        float inv = (end > beg) ? 1.f / (float)(end - beg) : 0.f;
        half8 o0, o1;
#pragma unroll
        for (int j = 0; j < 8; ++j) {
            o0[j] = (_Float16)((float)s0[j] * inv);
            o1[j] = (_Float16)((float)s1[j] * inv);
        }
        *(half8*)(&tile[w][ns][ch2 * 16])     = o0;
        *(half8*)(&tile[w][ns][ch2 * 16 + 8]) = o1;
    }
    // wave-private tile; DS ops complete in issue order per wave -> no barrier.

    int r = lane & 15;        // A-row / B-col / C-col
    int g = lane >> 4;        // k-subgroup

    // B fragments: [Wl;Wr] rows, K=128 split in 4 chunks of 32
    half8 bf[4][4];
#pragma unroll
    for (int kt = 0; kt < 4; ++kt) {
        const _Float16* Wm = (kt < 2) ? Wlh : Wrh;
        int kk = (kt & 1) * 32 + g * 8;
#pragma unroll
        for (int nt = 0; nt < 4; ++nt)
            bf[kt][nt] = *(const half8*)(Wm + (size_t)(nt * 16 + r) * D + kk);
    }

    f32x4 acc[4];
#pragma unroll
    for (int nt = 0; nt < 4; ++nt) {
        float bv = b[nt * 16 + r];
        acc[nt] = (f32x4){bv, bv, bv, bv};
    }

#pragma unroll
    for (int kt = 0; kt < 4; ++kt) {
        int kk = (kt & 1) * 32 + g * 8;
        half8 af;
        if (kt < 2) af = *(const half8*)(&tile[w][r][kk]);                 // aggr
        else        af = *(const half8*)(h + (size_t)(row0 + r) * D + kk); // self
#pragma unroll
        for (int nt = 0; nt < 4; ++nt)
            acc[nt] = __builtin_amdgcn_mfma_f32_16x16x32_f16(af, bf[kt][nt], acc[nt], 0, 0, 0);
    }

    // epilogue. C/D: col = lane&15, row = (lane>>4)*4 + q  [m89-verified]
    if (!PRJ) {
#pragma unroll
        for (int nt = 0; nt < 4; ++nt)
#pragma unroll
            for (int q = 0; q < 4; ++q) {
                int row = row0 + g * 4 + q;
                out[(size_t)row * D + nt * 16 + r] = (_Float16)fmaxf(acc[nt][q], 0.f);
            }
    } else {
        // stage relu(out) tile back to LDS (wave-private, in-order DS)
#pragma unroll
        for (int nt = 0; nt < 4; ++nt)
#pragma unroll
            for (int q = 0; q < 4; ++q)
                tile[w][g * 4 + q][nt * 16 + r] = (_Float16)fmaxf(acc[nt][q], 0.f);

        // B-frag of P rows {Wlo0,Wlo1,Wro0,Wro1} in cols 0..3
        half8 pf[2];
#pragma unroll
        for (int kt = 0; kt < 2; ++kt) {
            half8 t = {0, 0, 0, 0, 0, 0, 0, 0};
            if (r < 4) {
                const float* Pr = (r < 2) ? (Wlo + r * D) : (Wro + (r - 2) * D);
                int kk = kt * 32 + g * 8;
#pragma unroll
                for (int j = 0; j < 8; ++j) t[j] = (_Float16)Pr[kk + j];
            }
            pf[kt] = t;
        }
        f32x4 az = (f32x4){0.f, 0.f, 0.f, 0.f};
#pragma unroll
        for (int kt = 0; kt < 2; ++kt) {
            half8 af = *(const half8*)(&tile[w][r][kt * 32 + g * 8]);
            az = __builtin_amdgcn_mfma_f32_16x16x32_f16(af, pf[kt], az, 0, 0, 0);
        }
#pragma unroll
        for (int q = 0; q < 4; ++q) {
            int row = row0 + g * 4 + q;
            if (r < 2)      z12[row * 2 + r]       = az[q];
            else if (r < 4) z34[row * 2 + (r - 2)] = az[q];
        }
    }
}

// ---- edge-parallel pool: LDS partials + 8-way-split global atomic tail -----
// pool[(blockIdx&7)*256 + slot]: chain length = ZG/NPOOL = 128.
__global__ __launch_bounds__(256) void zpool_edge(
        const float2* __restrict__ z12, const float2* __restrict__ z34,
        const int* __restrict__ src, const int* __restrict__ dst,
        const int2* __restrict__ info, int E, float* __restrict__ pool) {
    __shared__ float lp[NGRAPHS * 2];
    int t = threadIdx.x;
    lp[t] = 0.f;
    __syncthreads();
    int tid = blockIdx.x * blockDim.x + t;
    int stride = gridDim.x * blockDim.x;
    for (int e = tid; e < E; e += stride) {
        int s = __builtin_nontemporal_load(src + e);
        int d = __builtin_nontemporal_load(dst + e);
        float2 z = z12[s];
        int2 nf = info[d];
        float w = __int_as_float(nf.y);
        atomicAdd(&lp[0 * NGRAPHS + nf.x], z.x * w);
        atomicAdd(&lp[1 * NGRAPHS + nf.x], z.y * w);
    }
    for (int i = tid; i < NNODES; i += stride) {
        float2 zi = z34[i];
        int g = info[i].x;
        atomicAdd(&lp[0 * NGRAPHS + g], zi.x);
        atomicAdd(&lp[1 * NGRAPHS + g], zi.y);
    }
    __syncthreads();
    float v = lp[t];
    if (v != 0.f) atomicAdd(&pool[(blockIdx.x & (NPOOL - 1)) * 256 + t], v);
}

// ---- final: sum 8 pool copies (fixed order), scale+bias --------------------
__global__ void out_kernel(const float* __restrict__ pool, const int* __restrict__ batch,
                           const float* __restrict__ bo, float* __restrict__ out) {
    int t = threadIdx.x;              // slot (j*128+g)
    float v = 0.f;
#pragma unroll
    for (int k = 0; k < NPOOL; ++k) v += pool[k * 256 + t];
    int j = t >> 7, g = t & 127;
    int c = lower_bound(batch, NNODES, g + 1) - lower_bound(batch, NNODES, g);
    out[g * 2 + j] = (c > 0) ? v / (float)c + bo[j] : 0.f;
}

// ---- launch ---------------------------------------------------------------

extern "C" void kernel_launch(void* const* d_in, const int* in_sizes, int n_in,
                              void* d_out, int out_size, void* d_ws, size_t ws_size,
                              hipStream_t stream) {
    const float* x    = (const float*)d_in[0];
    const int*   eidx = (const int*)d_in[1];
    const int*   batch= (const int*)d_in[2];
    const float* Wl   = (const float*)d_in[3];
    const float* Wr   = (const float*)d_in[4];
    const float* b    = (const float*)d_in[5];
    const float* Wlo  = (const float*)d_in[6];
    const float* Wro  = (const float*)d_in[7];
    const float* bo   = (const float*)d_in[8];

    int E = in_sizes[1] / 2;
    const int* src = eidx;
    const int* dst = eidx + E;

    char* ws = (char*)d_ws;
    size_t hb = (size_t)NNODES * D * 2;       // fp16 h buffer = 8,192,000 B
    _Float16* xh   = (_Float16*)ws;
    _Float16* bufA = (_Float16*)(ws + hb);
    char* p = ws + 2 * hb;
    _Float16* Wlh  = (_Float16*)p;  p += 3 * D * D * 2;
    _Float16* Wrh  = (_Float16*)p;  p += 3 * D * D * 2;
    int*    col  = (int*)p;     p += (size_t)E * 4;
    int*    offs = (int*)p;     p += ((size_t)(NNODES + 1) * 4 + 127) / 128 * 128;
    int2*   info = (int2*)p;    p += (size_t)NNODES * 8;
    float*  z12  = (float*)p;   p += (size_t)NNODES * 8;
    float*  z34  = (float*)p;   p += (size_t)NNODES * 8;
    int*    ecur = (int*)p;     p += 1024;
    float*  pool = (float*)p;   p += NPOOL * 256 * 4;
    int2*   elist= (int2*)p;    // 250 * 5120 * 8 = 10.24 MB

    hipMemsetAsync(ecur, 0, 1024, stream);

    int PB = (E + 4095) / 4096;      // 250 for E=1,024,000
    convert_partition<<<PB + CGRID, 256, 0, stream>>>(
        (const float4*)x, (half8*)xh, NNODES * D / 8,
        Wl, Wr, Wlh, Wrh, src, dst, E, ecur, elist, pool, PB);

    fill_block<<<NT, 1024, 0, stream>>>(elist, ecur, batch, offs, info, col);

    // L1: xh -> bufA ; L2: bufA -> xh ; L3: xh -> z12/z34 (no h3 materialized)
    layer_fused<0><<<1000, 256, 0, stream>>>(xh,   bufA, offs, col,
                                             Wlh,             Wrh,             b,
                                             nullptr, nullptr, nullptr, nullptr);
    layer_fused<0><<<1000, 256, 0, stream>>>(bufA, xh,   offs, col,
                                             Wlh + D * D,     Wrh + D * D,     b + D,
                                             nullptr, nullptr, nullptr, nullptr);
    layer_fused<1><<<1000, 256, 0, stream>>>(xh,   bufA, offs, col,
                                             Wlh + 2 * D * D, Wrh + 2 * D * D, b + 2 * D,
                                             Wlo, Wro, z12, z34);

    zpool_edge<<<ZG, 256, 0, stream>>>((const float2*)z12, (const float2*)z34,
                                       src, dst, info, E, pool);
    out_kernel<<<1, 256, 0, stream>>>(pool, batch, bo, (float*)d_out);
}

// Round 18
// 136.594 us; speedup vs baseline: 1.1448x; 1.0010x over previous
//
#include <hip/hip_runtime.h>

#define NNODES 64000
#define NGRAPHS 128
#define D 64
#define TP 72         // padded tile row (144B = 9 x 16B slots -> kills 16-way conflicts)
#define NT 250        // teams (node-range partitions), team = d >> 8
#define ESEG 5120     // per-team elist capacity (mean 4096, sigma ~63)
#define ZG 1024       // zpool grid
#define NPOOL 8       // pool split ways (atomic chain = ZG/NPOOL)
#define CGRID 2000    // convert-role blocks in fat kernel

typedef _Float16 half8 __attribute__((ext_vector_type(8)));
typedef float f32x4 __attribute__((ext_vector_type(4)));

__device__ __forceinline__ int lower_bound(const int* __restrict__ a, int n, int key) {
    int lo = 0, hi = n;
    while (lo < hi) {
        int mid = (lo + hi) >> 1;
        if (a[mid] < key) lo = mid + 1; else hi = mid;
    }
    return lo;
}

// ---- fat kernel: edge partition (blocks 0..PB-1) ∥ f32->f16 convert (rest) -
__global__ __launch_bounds__(256) void convert_partition(
        const float4* __restrict__ x, half8* __restrict__ xh, int n8,
        const float* __restrict__ Wl, const float* __restrict__ Wr,
        _Float16* __restrict__ Wlh, _Float16* __restrict__ Wrh,
        const int* __restrict__ src, const int* __restrict__ dst, int E,
        int* __restrict__ ecur, int2* __restrict__ elist,
        float* __restrict__ pool, int PB) {
    __shared__ int bcnt[256], bbase[256];
    int tid = threadIdx.x;
    if ((int)blockIdx.x < PB) {
        // ---- partition role: U=16, one 4096-edge chunk per block
        const int U = 16;
        int base = blockIdx.x * 256 * U;
        bcnt[tid] = 0;
        __syncthreads();
        int2 ed[U]; int team[U], slot[U];
#pragma unroll
        for (int u = 0; u < U; ++u) {
            int e = base + tid + u * 256;
            team[u] = -1;
            if (e < E) {
                int s = __builtin_nontemporal_load(src + e);
                int d = __builtin_nontemporal_load(dst + e);
                ed[u] = make_int2(s, d);
                team[u] = d >> 8;
                slot[u] = atomicAdd(&bcnt[team[u]], 1);
            }
        }
        __syncthreads();
        if (bcnt[tid] > 0) bbase[tid] = atomicAdd(&ecur[tid], bcnt[tid]);
        __syncthreads();
#pragma unroll
        for (int u = 0; u < U; ++u)
            if (team[u] >= 0)
                elist[(size_t)team[u] * ESEG + bbase[team[u]] + slot[u]] = ed[u];
    } else {
        // ---- convert role
        int bid = blockIdx.x - PB;              // 0..CGRID-1
        int i = bid * 256 + tid;
        int st = CGRID * 256;
        for (; i < n8; i += st) {
            float4 a = x[2 * i], b = x[2 * i + 1];
            half8 o;
            o[0] = (_Float16)a.x; o[1] = (_Float16)a.y; o[2] = (_Float16)a.z; o[3] = (_Float16)a.w;
            o[4] = (_Float16)b.x; o[5] = (_Float16)b.y; o[6] = (_Float16)b.z; o[7] = (_Float16)b.w;
            xh[i] = o;
        }
        int j = bid * 256 + tid;
        if (j < 3 * D * D) {
            Wlh[j] = (_Float16)Wl[j];
            Wrh[j] = (_Float16)Wr[j];
        }
        if (bid == 0) {
#pragma unroll
            for (int k = 0; k < NPOOL; ++k) pool[k * 256 + tid] = 0.f;
        }
    }
}

// ---- per-team CSR fill: elist staged in LDS, all per-edge atomics in LDS ---
__global__ __launch_bounds__(1024) void fill_block(
        const int2* __restrict__ elist, const int* __restrict__ ecur,
        const int* __restrict__ batch,
        int* __restrict__ offs, int2* __restrict__ info, int* __restrict__ col) {
    __shared__ int2 els[ESEG];                 // 40 KB staging
    __shared__ int lhist[256], lofs[256];
    int team = blockIdx.x;
    int t = threadIdx.x;
    int n = ecur[team];
    const int2* el = elist + (size_t)team * ESEG;

    // team-base scan (redundant per block, 1KB read, trivial)
    if (t < 256) lofs[t] = (t < NT) ? ecur[t] : 0;
    __syncthreads();
    for (int off = 1; off < 256; off <<= 1) {
        int x = 0;
        if (t < 256 && t >= off) x = lofs[t - off];
        __syncthreads();
        if (t < 256) lofs[t] += x;
        __syncthreads();
    }
    int tb = (team > 0) ? lofs[team - 1] : 0;
    if (team == NT - 1 && t == 0) offs[NNODES] = lofs[NT - 1];
    __syncthreads();

    if (t < 256) lhist[t] = 0;
    __syncthreads();
    for (int e = t; e < n; e += 1024) {
        int2 ed = el[e];
        els[e] = ed;
        atomicAdd(&lhist[ed.y & 255], 1);
    }
    __syncthreads();
    if (t < 256) lofs[t] = lhist[t];
    __syncthreads();
    for (int off = 1; off < 256; off <<= 1) {
        int x = 0;
        if (t < 256 && t >= off) x = lofs[t - off];
        __syncthreads();
        if (t < 256) lofs[t] += x;
        __syncthreads();
    }
    if (t < 256) {
        int v = lhist[t];
        int ex = lofs[t] - v;          // exclusive
        int gi = team * 256 + t;
        offs[gi] = tb + ex;
        float inv = (v > 0) ? 1.f / (float)v : 0.f;
        info[gi] = make_int2(batch[gi], __float_as_int(inv));
        lofs[t] = ex;                  // becomes write cursor
    }
    __syncthreads();
    for (int e = t; e < n; e += 1024) {
        int2 ed = els[e];
        int p = tb + atomicAdd(&lofs[ed.y & 255], 1);
        col[p] = ed.x;
    }
}

// ---- fused layer: single-pass 16-node gather -> padded LDS tile -> MFMA ----
// lane = (node-slot 0..15, 32B chunk 0..3); each lane owns 16 halfs of a row.
template <int PRJ>
__global__ __launch_bounds__(256) void layer_fused(
        const _Float16* __restrict__ h, _Float16* __restrict__ out,
        const int* __restrict__ offs, const int* __restrict__ col,
        const _Float16* __restrict__ Wlh, const _Float16* __restrict__ Wrh,
        const float* __restrict__ b,
        const float* __restrict__ Wlo, const float* __restrict__ Wro,
        float* __restrict__ z12, float* __restrict__ z34) {
    __shared__ _Float16 tile[4][16][TP];         // 144B row: conflict-free reads
    int lane = threadIdx.x & 63;
    int w    = threadIdx.x >> 6;
    int row0 = (blockIdx.x * 4 + w) * 16;

    // phase A: gather-mean, all 16 nodes in parallel
    {
        int ns  = lane >> 2;      // node slot 0..15
        int ch2 = lane & 3;       // 32B chunk 0..3
        int i = row0 + ns;
        int beg = offs[i], end = offs[i + 1];
        half8 s0 = {0, 0, 0, 0, 0, 0, 0, 0};
        half8 s1 = {0, 0, 0, 0, 0, 0, 0, 0};
        int e = beg;
        for (; e + 8 <= end; e += 8) {           // 16 x 16B loads in flight
            int c0 = col[e],     c1 = col[e + 1], c2 = col[e + 2], c3 = col[e + 3];
            int c4 = col[e + 4], c5 = col[e + 5], c6 = col[e + 6], c7 = col[e + 7];
            const _Float16* r0 = h + (size_t)c0 * D + ch2 * 16;
            const _Float16* r1 = h + (size_t)c1 * D + ch2 * 16;
            const _Float16* r2 = h + (size_t)c2 * D + ch2 * 16;
            const _Float16* r3 = h + (size_t)c3 * D + ch2 * 16;
            const _Float16* r4 = h + (size_t)c4 * D + ch2 * 16;
            const _Float16* r5 = h + (size_t)c5 * D + ch2 * 16;
            const _Float16* r6 = h + (size_t)c6 * D + ch2 * 16;
            const _Float16* r7 = h + (size_t)c7 * D + ch2 * 16;
            half8 a0 = *(const half8*)r0,       a1 = *(const half8*)r1;
            half8 a2 = *(const half8*)r2,       a3 = *(const half8*)r3;
            half8 a4 = *(const half8*)r4,       a5 = *(const half8*)r5;
            half8 a6 = *(const half8*)r6,       a7 = *(const half8*)r7;
            half8 b0 = *(const half8*)(r0 + 8), b1 = *(const half8*)(r1 + 8);
            half8 b2 = *(const half8*)(r2 + 8), b3 = *(const half8*)(r3 + 8);
            half8 b4 = *(const half8*)(r4 + 8), b5 = *(const half8*)(r5 + 8);
            half8 b6 = *(const half8*)(r6 + 8), b7 = *(const half8*)(r7 + 8);
            s0 += ((a0 + a1) + (a2 + a3)) + ((a4 + a5) + (a6 + a7));
            s1 += ((b0 + b1) + (b2 + b3)) + ((b4 + b5) + (b6 + b7));
        }
        for (; e + 4 <= end; e += 4) {
            int c0 = col[e], c1 = col[e + 1], c2 = col[e + 2], c3 = col[e + 3];
            const _Float16* r0 = h + (size_t)c0 * D + ch2 * 16;
            const _Float16* r1 = h + (size_t)c1 * D + ch2 * 16;
            const _Float16* r2 = h + (size_t)c2 * D + ch2 * 16;
            const _Float16* r3 = h + (size_t)c3 * D + ch2 * 16;
            half8 a0 = *(const half8*)r0,       a1 = *(const half8*)r1;
            half8 a2 = *(const half8*)r2,       a3 = *(const half8*)r3;
            half8 b0 = *(const half8*)(r0 + 8), b1 = *(const half8*)(r1 + 8);
            half8 b2 = *(const half8*)(r2 + 8), b3 = *(const half8*)(r3 + 8);
            s0 += (a0 + a1) + (a2 + a3);
            s1 += (b0 + b1) + (b2 + b3);
        }
        for (; e < end; ++e) {
            const _Float16* rp = h + (size_t)col[e] * D + ch2 * 16;
            s0 += *(const half8*)rp;
            s1 += *(const half8*)(rp + 8);
        }
        float inv = (end > beg) ? 1.f / (float)(end - beg) : 0.f;
        half8 o0, o1;
#pragma unroll
        for (int j = 0; j < 8; ++j) {
            o0[j] = (_Float16)((float)s0[j] * inv);
            o1[j] = (_Float16)((float)s1[j] * inv);
        }
        *(half8*)(&tile[w][ns][ch2 * 16])     = o0;
        *(half8*)(&tile[w][ns][ch2 * 16 + 8]) = o1;
    }
    // wave-private tile; DS ops complete in issue order per wave -> no barrier.

    int r = lane & 15;        // A-row / B-col / C-col
    int g = lane >> 4;        // k-subgroup

    // B fragments: [Wl;Wr] rows, K=128 split in 4 chunks of 32
    half8 bf[4][4];
#pragma unroll
    for (int kt = 0; kt < 4; ++kt) {
        const _Float16* Wm = (kt < 2) ? Wlh : Wrh;
        int kk = (kt & 1) * 32 + g * 8;
#pragma unroll
        for (int nt = 0; nt < 4; ++nt)
            bf[kt][nt] = *(const half8*)(Wm + (size_t)(nt * 16 + r) * D + kk);
    }

    f32x4 acc[4];
#pragma unroll
    for (int nt = 0; nt < 4; ++nt) {
        float bv = b[nt * 16 + r];
        acc[nt] = (f32x4){bv, bv, bv, bv};
    }

#pragma unroll
    for (int kt = 0; kt < 4; ++kt) {
        int kk = (kt & 1) * 32 + g * 8;
        half8 af;
        if (kt < 2) af = *(const half8*)(&tile[w][r][kk]);                 // aggr
        else        af = *(const half8*)(h + (size_t)(row0 + r) * D + kk); // self
#pragma unroll
        for (int nt = 0; nt < 4; ++nt)
            acc[nt] = __builtin_amdgcn_mfma_f32_16x16x32_f16(af, bf[kt][nt], acc[nt], 0, 0, 0);
    }

    // epilogue. C/D: col = lane&15, row = (lane>>4)*4 + q  [m89-verified]
    if (!PRJ) {
#pragma unroll
        for (int nt = 0; nt < 4; ++nt)
#pragma unroll
            for (int q = 0; q < 4; ++q) {
                int row = row0 + g * 4 + q;
                out[(size_t)row * D + nt * 16 + r] = (_Float16)fmaxf(acc[nt][q], 0.f);
            }
    } else {
        // stage relu(out) tile back to LDS (wave-private, in-order DS)
#pragma unroll
        for (int nt = 0; nt < 4; ++nt)
#pragma unroll
            for (int q = 0; q < 4; ++q)
                tile[w][g * 4 + q][nt * 16 + r] = (_Float16)fmaxf(acc[nt][q], 0.f);

        // B-frag of P rows {Wlo0,Wlo1,Wro0,Wro1} in cols 0..3
        half8 pf[2];
#pragma unroll
        for (int kt = 0; kt < 2; ++kt) {
            half8 t = {0, 0, 0, 0, 0, 0, 0, 0};
            if (r < 4) {
                const float* Pr = (r < 2) ? (Wlo + r * D) : (Wro + (r - 2) * D);
                int kk = kt * 32 + g * 8;
#pragma unroll
                for (int j = 0; j < 8; ++j) t[j] = (_Float16)Pr[kk + j];
            }
            pf[kt] = t;
        }
        f32x4 az = (f32x4){0.f, 0.f, 0.f, 0.f};
#pragma unroll
        for (int kt = 0; kt < 2; ++kt) {
            half8 af = *(const half8*)(&tile[w][r][kt * 32 + g * 8]);
            az = __builtin_amdgcn_mfma_f32_16x16x32_f16(af, pf[kt], az, 0, 0, 0);
        }
#pragma unroll
        for (int q = 0; q < 4; ++q) {
            int row = row0 + g * 4 + q;
            if (r < 2)      z12[row * 2 + r]       = az[q];
            else if (r < 4) z34[row * 2 + (r - 2)] = az[q];
        }
    }
}

// ---- edge-parallel pool: LDS partials + 8-way-split global atomic tail -----
__global__ __launch_bounds__(256) void zpool_edge(
        const float2* __restrict__ z12, const float2* __restrict__ z34,
        const int* __restrict__ src, const int* __restrict__ dst,
        const int2* __restrict__ info, int E, float* __restrict__ pool) {
    __shared__ float lp[NGRAPHS * 2];
    int t = threadIdx.x;
    lp[t] = 0.f;
    __syncthreads();
    int tid = blockIdx.x * blockDim.x + t;
    int stride = gridDim.x * blockDim.x;
    for (int e = tid; e < E; e += stride) {
        int s = __builtin_nontemporal_load(src + e);
        int d = __builtin_nontemporal_load(dst + e);
        float2 z = z12[s];
        int2 nf = info[d];
        float w = __int_as_float(nf.y);
        atomicAdd(&lp[0 * NGRAPHS + nf.x], z.x * w);
        atomicAdd(&lp[1 * NGRAPHS + nf.x], z.y * w);
    }
    for (int i = tid; i < NNODES; i += stride) {
        float2 zi = z34[i];
        int g = info[i].x;
        atomicAdd(&lp[0 * NGRAPHS + g], zi.x);
        atomicAdd(&lp[1 * NGRAPHS + g], zi.y);
    }
    __syncthreads();
    float v = lp[t];
    if (v != 0.f) atomicAdd(&pool[(blockIdx.x & (NPOOL - 1)) * 256 + t], v);
}

// ---- final: sum 8 pool copies (fixed order), scale+bias --------------------
__global__ void out_kernel(const float* __restrict__ pool, const int* __restrict__ batch,
                           const float* __restrict__ bo, float* __restrict__ out) {
    int t = threadIdx.x;              // slot (j*128+g)
    float v = 0.f;
#pragma unroll
    for (int k = 0; k < NPOOL; ++k) v += pool[k * 256 + t];
    int j = t >> 7, g = t & 127;
    int c = lower_bound(batch, NNODES, g + 1) - lower_bound(batch, NNODES, g);
    out[g * 2 + j] = (c > 0) ? v / (float)c + bo[j] : 0.f;
}

// ---- launch ---------------------------------------------------------------

extern "C" void kernel_launch(void* const* d_in, const int* in_sizes, int n_in,
                              void* d_out, int out_size, void* d_ws, size_t ws_size,
                              hipStream_t stream) {
    const float* x    = (const float*)d_in[0];
    const int*   eidx = (const int*)d_in[1];
    const int*   batch= (const int*)d_in[2];
    const float* Wl   = (const float*)d_in[3];
    const float* Wr   = (const float*)d_in[4];
    const float* b    = (const float*)d_in[5];
    const float* Wlo  = (const float*)d_in[6];
    const float* Wro  = (const float*)d_in[7];
    const float* bo   = (const float*)d_in[8];

    int E = in_sizes[1] / 2;
    const int* src = eidx;
    const int* dst = eidx + E;

    char* ws = (char*)d_ws;
    size_t hb = (size_t)NNODES * D * 2;       // fp16 h buffer = 8,192,000 B
    _Float16* xh   = (_Float16*)ws;
    _Float16* bufA = (_Float16*)(ws + hb);
    char* p = ws + 2 * hb;
    _Float16* Wlh  = (_Float16*)p;  p += 3 * D * D * 2;
    _Float16* Wrh  = (_Float16*)p;  p += 3 * D * D * 2;
    int*    col  = (int*)p;     p += (size_t)E * 4;
    int*    offs = (int*)p;     p += ((size_t)(NNODES + 1) * 4 + 127) / 128 * 128;
    int2*   info = (int2*)p;    p += (size_t)NNODES * 8;
    float*  z12  = (float*)p;   p += (size_t)NNODES * 8;
    float*  z34  = (float*)p;   p += (size_t)NNODES * 8;
    int*    ecur = (int*)p;     p += 1024;
    float*  pool = (float*)p;   p += NPOOL * 256 * 4;
    int2*   elist= (int2*)p;    // 250 * 5120 * 8 = 10.24 MB

    hipMemsetAsync(ecur, 0, 1024, stream);

    int PB = (E + 4095) / 4096;      // 250 for E=1,024,000
    convert_partition<<<PB + CGRID, 256, 0, stream>>>(
        (const float4*)x, (half8*)xh, NNODES * D / 8,
        Wl, Wr, Wlh, Wrh, src, dst, E, ecur, elist, pool, PB);

    fill_block<<<NT, 1024, 0, stream>>>(elist, ecur, batch, offs, info, col);

    // L1: xh -> bufA ; L2: bufA -> xh ; L3: xh -> z12/z34 (no h3 materialized)
    layer_fused<0><<<1000, 256, 0, stream>>>(xh,   bufA, offs, col,
                                             Wlh,             Wrh,             b,
                                             nullptr, nullptr, nullptr, nullptr);
    layer_fused<0><<<1000, 256, 0, stream>>>(bufA, xh,   offs, col,
                                             Wlh + D * D,     Wrh + D * D,     b + D,
                                             nullptr, nullptr, nullptr, nullptr);
    layer_fused<1><<<1000, 256, 0, stream>>>(xh,   bufA, offs, col,
                                             Wlh + 2 * D * D, Wrh + 2 * D * D, b + 2 * D,
                                             Wlo, Wro, z12, z34);

    zpool_edge<<<ZG, 256, 0, stream>>>((const float2*)z12, (const float2*)z34,
                                       src, dst, info, E, pool);
    out_kernel<<<1, 256, 0, stream>>>(pool, batch, bo, (float*)d_out);
}